// Round 6
// baseline (175.425 us; speedup 1.0000x reference)
//
#include <hip/hip_runtime.h>
#include <stdint.h>

#define NB 2
#define NS 2048
#define ND 1024
#define NH 16
#define NHD 64
#define NM (NB*NS)   // 4096

typedef __bf16 bf16;
typedef float f32x4 __attribute__((ext_vector_type(4)));
typedef __bf16 bf16x8 __attribute__((ext_vector_type(8)));
typedef __bf16 bf16x4 __attribute__((ext_vector_type(4)));

#define MFMA16(a,b,c) __builtin_amdgcn_mfma_f32_16x16x32_bf16(a,b,c,0,0,0)

__device__ __forceinline__ void gld_lds16(const bf16* g, bf16* l) {
  __builtin_amdgcn_global_load_lds((const __attribute__((address_space(1))) void*)g,
                                   (__attribute__((address_space(3))) void*)l,
                                   16, 0, 0);
}

// ---------------- fp32 -> bf16 conversion, 3 equal tensors (Q,K,V) -------
__global__ __launch_bounds__(256)
void cvt3(const float* __restrict__ s0, const float* __restrict__ s1,
          const float* __restrict__ s2, bf16* __restrict__ dst, int n4each) {
  const int t = blockIdx.y;
  const float* s = (t == 0) ? s0 : (t == 1) ? s1 : s2;
  int i = blockIdx.x * blockDim.x + threadIdx.x;
  if (i >= n4each) return;
  float4 v = ((const float4*)s)[i];
  bf16x4 o = { (bf16)v.x, (bf16)v.y, (bf16)v.z, (bf16)v.w };
  ((bf16x4*)(dst + (size_t)t * n4each * 4))[i] = o;
}

// ---------------- fp32 -> bf16 conversion, 4 weight matrices --------------
__global__ __launch_bounds__(256)
void cvt_w4(const float* __restrict__ s0, const float* __restrict__ s1,
            const float* __restrict__ s2, const float* __restrict__ s3,
            bf16* __restrict__ dst, int n4each) {
  const int t = blockIdx.y;
  const float* s = (t == 0) ? s0 : (t == 1) ? s1 : (t == 2) ? s2 : s3;
  int i = blockIdx.x * blockDim.x + threadIdx.x;
  if (i >= n4each) return;
  float4 v = ((const float4*)s)[i];
  bf16x4 o = { (bf16)v.x, (bf16)v.y, (bf16)v.z, (bf16)v.w };
  ((bf16x4*)(dst + (size_t)t * n4each * 4))[i] = o;
}

// ---------------- NT GEMM: C[m,n] = sum_k A[m,k]*W[n,k] + bias[n] --------
// MODE 0: QKV projection; fused RoPE (t<2); q additionally scaled by
//         (1/sqrt(HD))*log2(e) so attention softmax can use exp2.
//         bf16 out scattered to [B,H,S,HD] (z = tensor 0..2)
// MODE 1: output projection, fp32 out row-major [M, D]
template<int MODE>
__global__ __launch_bounds__(256)
void gemm_nt(const bf16* __restrict__ A, const bf16* __restrict__ W,
             const float* __restrict__ b0, const float* __restrict__ b1,
             const float* __restrict__ b2,
             const float* __restrict__ fc, const float* __restrict__ fs,
             bf16* __restrict__ obf, float* __restrict__ of) {
  constexpr int K = ND;
  __shared__ __align__(16) bf16 As[128 * 32];
  __shared__ __align__(16) bf16 Bs[128 * 32];
  const int tid = threadIdx.x;
  const int w = tid >> 6, lane = tid & 63;
  const int nt = blockIdx.x, mt = blockIdx.y, t = blockIdx.z;
  const bf16* Ab = A + (size_t)t * ((size_t)NM * K);
  const bf16* Wb = W + (size_t)t * ((size_t)ND * K);
  const float* bias = (t == 0) ? b0 : (t == 1) ? b1 : b2;
  const int wr = (w >> 1) * 64, wc = (w & 1) * 64;
  f32x4 acc[4][4] = {};
  const bf16* ga = Ab + (size_t)(mt * 128 + (tid >> 2)) * K + (tid & 3) * 8;
  const bf16* gb = Wb + (size_t)(nt * 128 + (tid >> 2)) * K + (tid & 3) * 8;
  bf16* lA = As + w * 512;   // wave-uniform LDS base (gld_lds writes base + lane*16)
  bf16* lB = Bs + w * 512;
  for (int k0 = 0; k0 < K; k0 += 32) {
    __syncthreads();
    gld_lds16(ga + k0, lA);
    gld_lds16(ga + (size_t)64 * K + k0, lA + 64 * 32);
    gld_lds16(gb + k0, lB);
    gld_lds16(gb + (size_t)64 * K + k0, lB + 64 * 32);
    __syncthreads();   // compiler drains vmcnt(0) before s_barrier -> LDS ready
    bf16x8 af[4], bfr[4];
#pragma unroll
    for (int i = 0; i < 4; ++i) {
      af[i]  = *(const bf16x8*)&As[(wr + i * 16 + (lane & 15)) * 32 + (lane >> 4) * 8];
      bfr[i] = *(const bf16x8*)&Bs[(wc + i * 16 + (lane & 15)) * 32 + (lane >> 4) * 8];
    }
#pragma unroll
    for (int i = 0; i < 4; ++i)
#pragma unroll
      for (int j = 0; j < 4; ++j)
        acc[i][j] = MFMA16(af[i], bfr[j], acc[i][j]);
  }
#pragma unroll
  for (int i = 0; i < 4; ++i) {
#pragma unroll
    for (int j = 0; j < 4; ++j) {
      const int gcol = nt * 128 + wc + j * 16 + (lane & 15);
      const float bv = bias[gcol];
#pragma unroll
      for (int r = 0; r < 4; ++r) {
        const int grow = mt * 128 + wr + i * 16 + (lane >> 4) * 4 + r;
        float v = acc[i][j][r] + bv;
        if (MODE == 0) {
          const int b = grow >> 11, s = grow & (NS - 1);
          const int h = gcol >> 6, hd = gcol & 63;
          if (t < 2) {   // fused RoPE: lane pairs hold adjacent hd columns
            float pv = __shfl_xor(v, 1);
            const int ii = hd >> 1;
            float c  = fc[(s << 5) + ii];
            float sn = fs[(s << 5) + ii];
            // even hd: out_r = xr*c - xi*s   (v=xr, pv=xi)
            // odd  hd: out_i = xr*s + xi*c   (v=xi, pv=xr)
            v = ((hd & 1) == 0) ? (v * c - pv * sn) : (pv * sn + v * c);
            if (t == 0) v *= 0.18033688011112042f;   // (1/sqrt(HD)) * log2(e)
          }
          obf[(size_t)t * ((size_t)NM * ND) +
              (((size_t)(b * NH + h) * NS + s) * NHD + hd)] = (bf16)v;
        } else {
          of[(size_t)grow * ND + gcol] = v;
        }
      }
    }
  }
}

// ---------------- V transpose: [BH, S, 64] -> [BH, 64, S] ----------------
__global__ __launch_bounds__(256)
void transpose_v(const bf16* __restrict__ v, bf16* __restrict__ vt) {
  __shared__ __align__(16) bf16 t[64][72];
  const int s0 = blockIdx.x * 64;
  const int bh = blockIdx.y;
  const bf16* src = v + ((size_t)bh * NS + s0) * NHD;
#pragma unroll
  for (int it = 0; it < 2; ++it) {
    int slot = threadIdx.x + it * 256;
    int r = slot >> 3, c8 = (slot & 7) * 8;
    *(bf16x8*)&t[r][c8] = *(const bf16x8*)&src[(size_t)r * NHD + c8];
  }
  __syncthreads();
  bf16* dst = vt + (size_t)bh * NHD * NS + s0;
#pragma unroll
  for (int it = 0; it < 2; ++it) {
    int slot = threadIdx.x + it * 256;
    int r = slot >> 3, c8 = (slot & 7) * 8;   // r = hd row of output, c8 = s offset
    bf16x8 vv;
#pragma unroll
    for (int e = 0; e < 8; ++e) vv[e] = t[c8 + e][r];
    *(bf16x8*)&dst[(size_t)r * NS + c8] = vv;
  }
}

// ---------------- flash attention, causal -------------------------------
// Barrier-free k-loop: K/V fragments read directly from global (L2-resident:
// K+V per bh = 512 KB; bh is the fast grid dim so all 32 blocks of a bh land
// on XCD bh%8 -> 2 MB working set per 4-MiB L2). Wave owns 32 q-rows (2x16
// subtiles); the 4 waves of a block split each tile's k-range 4-way
// (kt == w mod 4) and merge (m,l,o) flash-decoding style via LDS at tile end.
// Block covers tile pair (j, 63-j): every wave chip-wide does ~8-9 k-tiles.
// Swapped-operand MFMAs keep softmax per-lane scalar; softmax in base-2.
__global__ __launch_bounds__(256)
void attn_k(const bf16* __restrict__ q, const bf16* __restrict__ k,
            const bf16* __restrict__ vt, bf16* __restrict__ out) {
  __shared__ __align__(16) bf16 P[4][2][16][72];    // [wave][sub][q-row][k]
  __shared__ __align__(16) bf16 MO[4][2][16][64];   // merge: o (bf16)
  __shared__ float ML[4][2][16][2];                 // merge: m, l
  const int w = threadIdx.x >> 6, lane = threadIdx.x & 63;
  const int qrow = lane & 15, grp = lane >> 4;
  const int bh = blockIdx.x;                        // fast dim -> XCD = bh & 7
  const int j = blockIdx.y;
  const int b = bh >> 4, h = bh & (NH - 1);

  const bf16* qb = q + (size_t)bh * NS * NHD;
  const bf16* kb = k + (size_t)bh * NS * NHD;
  const bf16* vb = vt + (size_t)bh * NHD * NS;

#pragma unroll
  for (int half = 0; half < 2; ++half) {
    const int t = half ? (63 - j) : j;      // 32-row q-tile index
    const int n = (t >> 1) + 1;             // # of 64-wide k-tiles (causal)
    const int q0 = t * 32;

    bf16x8 qf[2][2];                        // [sub][ch]
#pragma unroll
    for (int sub = 0; sub < 2; ++sub)
#pragma unroll
      for (int ch = 0; ch < 2; ++ch)
        qf[sub][ch] = *(const bf16x8*)&qb[(size_t)(q0 + sub * 16 + qrow) * NHD +
                                          ch * 32 + grp * 8];

    f32x4 o[2][4] = {};
    float m[2] = {-1e30f, -1e30f}, l[2] = {0.f, 0.f};

    for (int kt = w; kt < n; kt += 4) {     // this wave's quarter of k-tiles
      const int kk0 = kt * 64;

      bf16x8 kf[4][2];                      // full K tile, direct from L2
#pragma unroll
      for (int cb = 0; cb < 4; ++cb)
#pragma unroll
        for (int ch = 0; ch < 2; ++ch)
          kf[cb][ch] = *(const bf16x8*)&kb[(size_t)(kk0 + cb * 16 + qrow) * NHD +
                                           ch * 32 + grp * 8];

#pragma unroll
      for (int sub = 0; sub < 2; ++sub) {
        f32x4 sc[4] = {};
        __builtin_amdgcn_s_setprio(1);
#pragma unroll
        for (int ch = 0; ch < 2; ++ch)
#pragma unroll
          for (int cb = 0; cb < 4; ++cb)
            sc[cb] = MFMA16(kf[cb][ch], qf[sub][ch], sc[cb]);   // S^T[k][q]
        __builtin_amdgcn_s_setprio(0);

        if (kt == n - 1) {                  // only the last k-tile is diagonal
          const int qi = q0 + sub * 16 + qrow;
#pragma unroll
          for (int cb = 0; cb < 4; ++cb)
#pragma unroll
            for (int r = 0; r < 4; ++r)
              if (kk0 + cb * 16 + grp * 4 + r > qi) sc[cb][r] = -1e30f;
        }

        float pm = sc[0][0];
#pragma unroll
        for (int cb = 0; cb < 4; ++cb)
#pragma unroll
          for (int r = 0; r < 4; ++r) pm = fmaxf(pm, sc[cb][r]);
        pm = fmaxf(pm, __shfl_xor(pm, 16));
        pm = fmaxf(pm, __shfl_xor(pm, 32));
        const float mn = fmaxf(m[sub], pm);
        const float scl = exp2f(m[sub] - mn);
        m[sub] = mn;
        l[sub] *= scl;
#pragma unroll
        for (int cb = 0; cb < 4; ++cb) {
          bf16x4 pk;
#pragma unroll
          for (int r = 0; r < 4; ++r) {
            float p = exp2f(sc[cb][r] - mn);
            l[sub] += p;
            pk[r] = (bf16)p;
          }
          *(bf16x4*)&P[w][sub][qrow][cb * 16 + grp * 4] = pk;
        }
#pragma unroll
        for (int hb = 0; hb < 4; ++hb)
#pragma unroll
          for (int r = 0; r < 4; ++r) o[sub][hb][r] *= scl;
      }

      __builtin_amdgcn_s_setprio(1);
#pragma unroll
      for (int ch = 0; ch < 2; ++ch) {
        bf16x8 pa0 = *(const bf16x8*)&P[w][0][qrow][ch * 32 + grp * 8];
        bf16x8 pa1 = *(const bf16x8*)&P[w][1][qrow][ch * 32 + grp * 8];
#pragma unroll
        for (int hb = 0; hb < 4; ++hb) {
          bf16x8 vf = *(const bf16x8*)&vb[(size_t)(hb * 16 + qrow) * NS +
                                          kk0 + ch * 32 + grp * 8];
          o[0][hb] = MFMA16(vf, pa0, o[0][hb]);     // O^T[hd][q]
          o[1][hb] = MFMA16(vf, pa1, o[1][hb]);
        }
      }
      __builtin_amdgcn_s_setprio(0);
    }

    // full row-sum of l (4 lanes share each q-row)
#pragma unroll
    for (int sub = 0; sub < 2; ++sub) {
      l[sub] += __shfl_xor(l[sub], 16);
      l[sub] += __shfl_xor(l[sub], 32);
    }

    __syncthreads();   // (half==1: also guarantees prior merges done reading MO/ML)

    // publish this wave's partial state
#pragma unroll
    for (int sub = 0; sub < 2; ++sub) {
#pragma unroll
      for (int hb = 0; hb < 4; ++hb) {
        bf16x4 ov = { (bf16)o[sub][hb][0], (bf16)o[sub][hb][1],
                      (bf16)o[sub][hb][2], (bf16)o[sub][hb][3] };
        *(bf16x4*)&MO[w][sub][qrow][hb * 16 + grp * 4] = ov;
      }
      if (grp == 0) {
        ML[w][sub][qrow][0] = m[sub];
        ML[w][sub][qrow][1] = l[sub];
      }
    }

    __syncthreads();

    // merge 4 k-quarters + store (wave 0 -> sub 0, wave 1 -> sub 1)
    if (w < 2) {
      const int sub = w;
      float mm = -1e30f;
#pragma unroll
      for (int sw = 0; sw < 4; ++sw) mm = fmaxf(mm, ML[sw][sub][qrow][0]);
      float ll = 0.f;
      f32x4 oo[4] = {};
#pragma unroll
      for (int sw = 0; sw < 4; ++sw) {
        const float sc2 = exp2f(ML[sw][sub][qrow][0] - mm);
        ll += ML[sw][sub][qrow][1] * sc2;
#pragma unroll
        for (int hb = 0; hb < 4; ++hb) {
          bf16x4 t4 = *(const bf16x4*)&MO[sw][sub][qrow][hb * 16 + grp * 4];
#pragma unroll
          for (int r = 0; r < 4; ++r) oo[hb][r] += (float)t4[r] * sc2;
        }
      }
      const float inv = 1.f / ll;
      const int s = q0 + sub * 16 + qrow;
      bf16* op = out + (size_t)(b * NS + s) * ND + h * NHD + grp * 4;
#pragma unroll
      for (int hb = 0; hb < 4; ++hb) {
        bf16x4 ov = { (bf16)(oo[hb][0] * inv), (bf16)(oo[hb][1] * inv),
                      (bf16)(oo[hb][2] * inv), (bf16)(oo[hb][3] * inv) };
        *(bf16x4*)&op[hb * 16] = ov;
      }
    }
  }
}

// -------------------------------------------------------------------------
extern "C" void kernel_launch(void* const* d_in, const int* in_sizes, int n_in,
                              void* d_out, int out_size, void* d_ws, size_t ws_size,
                              hipStream_t stream) {
  const float* Q  = (const float*)d_in[0];
  const float* K  = (const float*)d_in[1];
  const float* V  = (const float*)d_in[2];
  // d_in[3] = mask (causal, known analytically -> unused)
  const float* fc = (const float*)d_in[4];
  const float* fs = (const float*)d_in[5];
  const float* wq = (const float*)d_in[6];
  const float* bq = (const float*)d_in[7];
  const float* wk = (const float*)d_in[8];
  const float* bk = (const float*)d_in[9];
  const float* wv = (const float*)d_in[10];
  const float* bv = (const float*)d_in[11];
  const float* wo = (const float*)d_in[12];
  const float* bo = (const float*)d_in[13];
  float* out = (float*)d_out;
  bf16* ws = (bf16*)d_ws;

  const size_t MB_ = 1024 * 1024;  // elements
  bf16* Qbf  = ws;                     // 3 x 4M elems (Q,K,V bf16)
  bf16* Wqkv = ws + 12 * MB_;          // 3 x 1M (wq, wk, wv)
  bf16* Wo   = ws + 15 * MB_;          // 1M
  bf16* qp   = ws + 16 * MB_;          // q' [BH,S,HD] 4M
  bf16* kp   = ws + 20 * MB_;          // k' 4M
  bf16* vp   = ws + 24 * MB_;          // v' 4M
  bf16* vtp  = ws + 28 * MB_;          // v transposed [BH,HD,S] 4M
  bf16* aout = ws + 32 * MB_;          // attention output [M, D] 4M

  cvt3<<<dim3(4096, 3), 256, 0, stream>>>(Q, K, V, Qbf, 1048576);
  cvt_w4<<<dim3(1024, 4), 256, 0, stream>>>(wq, wk, wv, wo, Wqkv, 262144);

  gemm_nt<0><<<dim3(8, 32, 3), 256, 0, stream>>>(Qbf, Wqkv, bq, bk, bv, fc, fs, qp, nullptr);

  transpose_v<<<dim3(32, 32), 256, 0, stream>>>(vp, vtp);

  attn_k<<<dim3(32, 32), 256, 0, stream>>>(qp, kp, vtp, aout);

  gemm_nt<1><<<dim3(8, 32, 1), 256, 0, stream>>>(aout, Wo, bo, bo, bo, fc, fs, nullptr, out);
}

// Round 7
// 144.058 us; speedup vs baseline: 1.2177x; 1.2177x over previous
//
#include <hip/hip_runtime.h>
#include <stdint.h>

#define NB 2
#define NS 2048
#define ND 1024
#define NH 16
#define NHD 64
#define NM (NB*NS)   // 4096

typedef __bf16 bf16;
typedef float f32x4 __attribute__((ext_vector_type(4)));
typedef __bf16 bf16x8 __attribute__((ext_vector_type(8)));
typedef __bf16 bf16x4 __attribute__((ext_vector_type(4)));

#define MFMA16(a,b,c) __builtin_amdgcn_mfma_f32_16x16x32_bf16(a,b,c,0,0,0)

__device__ __forceinline__ void gld_lds16(const bf16* g, bf16* l) {
  __builtin_amdgcn_global_load_lds((const __attribute__((address_space(1))) void*)g,
                                   (__attribute__((address_space(3))) void*)l,
                                   16, 0, 0);
}

// Barrier that drains LDS ops but leaves global loads in flight (vmcnt
// untouched) — unlike __syncthreads(), which drains vmcnt(0).
__device__ __forceinline__ void block_sync_lds() {
  asm volatile("s_waitcnt lgkmcnt(0)\n\ts_barrier" ::: "memory");
}

// ---------------- fp32 -> bf16 conversion, 3 equal tensors (Q,K,V) -------
__global__ __launch_bounds__(256)
void cvt3(const float* __restrict__ s0, const float* __restrict__ s1,
          const float* __restrict__ s2, bf16* __restrict__ dst, int n4each) {
  const int t = blockIdx.y;
  const float* s = (t == 0) ? s0 : (t == 1) ? s1 : s2;
  int i = blockIdx.x * blockDim.x + threadIdx.x;
  if (i >= n4each) return;
  float4 v = ((const float4*)s)[i];
  bf16x4 o = { (bf16)v.x, (bf16)v.y, (bf16)v.z, (bf16)v.w };
  ((bf16x4*)(dst + (size_t)t * n4each * 4))[i] = o;
}

// ---------------- fp32 -> bf16 conversion, 4 weight matrices --------------
__global__ __launch_bounds__(256)
void cvt_w4(const float* __restrict__ s0, const float* __restrict__ s1,
            const float* __restrict__ s2, const float* __restrict__ s3,
            bf16* __restrict__ dst, int n4each) {
  const int t = blockIdx.y;
  const float* s = (t == 0) ? s0 : (t == 1) ? s1 : (t == 2) ? s2 : s3;
  int i = blockIdx.x * blockDim.x + threadIdx.x;
  if (i >= n4each) return;
  float4 v = ((const float4*)s)[i];
  bf16x4 o = { (bf16)v.x, (bf16)v.y, (bf16)v.z, (bf16)v.w };
  ((bf16x4*)(dst + (size_t)t * n4each * 4))[i] = o;
}

// ---------------- NT GEMM: C[m,n] = sum_k A[m,k]*W[n,k] + bias[n] --------
// MODE 0: QKV projection; fused RoPE (t<2); q additionally scaled by
//         (1/sqrt(HD))*log2(e) so attention softmax can use exp2.
//         bf16 out scattered to [B,H,S,HD] (z = tensor 0..2)
// MODE 1: output projection, fp32 out row-major [M, D]
template<int MODE>
__global__ __launch_bounds__(256)
void gemm_nt(const bf16* __restrict__ A, const bf16* __restrict__ W,
             const float* __restrict__ b0, const float* __restrict__ b1,
             const float* __restrict__ b2,
             const float* __restrict__ fc, const float* __restrict__ fs,
             bf16* __restrict__ obf, float* __restrict__ of) {
  constexpr int K = ND;
  __shared__ __align__(16) bf16 As[128 * 32];
  __shared__ __align__(16) bf16 Bs[128 * 32];
  const int tid = threadIdx.x;
  const int w = tid >> 6, lane = tid & 63;
  const int nt = blockIdx.x, mt = blockIdx.y, t = blockIdx.z;
  const bf16* Ab = A + (size_t)t * ((size_t)NM * K);
  const bf16* Wb = W + (size_t)t * ((size_t)ND * K);
  const float* bias = (t == 0) ? b0 : (t == 1) ? b1 : b2;
  const int wr = (w >> 1) * 64, wc = (w & 1) * 64;
  f32x4 acc[4][4] = {};
  const bf16* ga = Ab + (size_t)(mt * 128 + (tid >> 2)) * K + (tid & 3) * 8;
  const bf16* gb = Wb + (size_t)(nt * 128 + (tid >> 2)) * K + (tid & 3) * 8;
  bf16* lA = As + w * 512;   // wave-uniform LDS base (gld_lds writes base + lane*16)
  bf16* lB = Bs + w * 512;
  for (int k0 = 0; k0 < K; k0 += 32) {
    __syncthreads();
    gld_lds16(ga + k0, lA);
    gld_lds16(ga + (size_t)64 * K + k0, lA + 64 * 32);
    gld_lds16(gb + k0, lB);
    gld_lds16(gb + (size_t)64 * K + k0, lB + 64 * 32);
    __syncthreads();   // compiler drains vmcnt(0) before s_barrier -> LDS ready
    bf16x8 af[4], bfr[4];
#pragma unroll
    for (int i = 0; i < 4; ++i) {
      af[i]  = *(const bf16x8*)&As[(wr + i * 16 + (lane & 15)) * 32 + (lane >> 4) * 8];
      bfr[i] = *(const bf16x8*)&Bs[(wc + i * 16 + (lane & 15)) * 32 + (lane >> 4) * 8];
    }
#pragma unroll
    for (int i = 0; i < 4; ++i)
#pragma unroll
      for (int j = 0; j < 4; ++j)
        acc[i][j] = MFMA16(af[i], bfr[j], acc[i][j]);
  }
#pragma unroll
  for (int i = 0; i < 4; ++i) {
#pragma unroll
    for (int j = 0; j < 4; ++j) {
      const int gcol = nt * 128 + wc + j * 16 + (lane & 15);
      const float bv = bias[gcol];
#pragma unroll
      for (int r = 0; r < 4; ++r) {
        const int grow = mt * 128 + wr + i * 16 + (lane >> 4) * 4 + r;
        float v = acc[i][j][r] + bv;
        if (MODE == 0) {
          const int b = grow >> 11, s = grow & (NS - 1);
          const int h = gcol >> 6, hd = gcol & 63;
          if (t < 2) {   // fused RoPE: lane pairs hold adjacent hd columns
            float pv = __shfl_xor(v, 1);
            const int ii = hd >> 1;
            float c  = fc[(s << 5) + ii];
            float sn = fs[(s << 5) + ii];
            // even hd: out_r = xr*c - xi*s   (v=xr, pv=xi)
            // odd  hd: out_i = xr*s + xi*c   (v=xi, pv=xr)
            v = ((hd & 1) == 0) ? (v * c - pv * sn) : (pv * sn + v * c);
            if (t == 0) v *= 0.18033688011112042f;   // (1/sqrt(HD)) * log2(e)
          }
          obf[(size_t)t * ((size_t)NM * ND) +
              (((size_t)(b * NH + h) * NS + s) * NHD + hd)] = (bf16)v;
        } else {
          of[(size_t)grow * ND + gcol] = v;
        }
      }
    }
  }
}

// ---------------- V transpose: [BH, S, 64] -> [BH, 64, S] ----------------
__global__ __launch_bounds__(256)
void transpose_v(const bf16* __restrict__ v, bf16* __restrict__ vt) {
  __shared__ __align__(16) bf16 t[64][72];
  const int s0 = blockIdx.x * 64;
  const int bh = blockIdx.y;
  const bf16* src = v + ((size_t)bh * NS + s0) * NHD;
#pragma unroll
  for (int it = 0; it < 2; ++it) {
    int slot = threadIdx.x + it * 256;
    int r = slot >> 3, c8 = (slot & 7) * 8;
    *(bf16x8*)&t[r][c8] = *(const bf16x8*)&src[(size_t)r * NHD + c8];
  }
  __syncthreads();
  bf16* dst = vt + (size_t)bh * NHD * NS + s0;
#pragma unroll
  for (int it = 0; it < 2; ++it) {
    int slot = threadIdx.x + it * 256;
    int r = slot >> 3, c8 = (slot & 7) * 8;   // r = hd row of output, c8 = s offset
    bf16x8 vv;
#pragma unroll
    for (int e = 0; e < 8; ++e) vv[e] = t[c8 + e][r];
    *(bf16x8*)&dst[(size_t)r * NS + c8] = vv;
  }
}

// ---------------- one 64-k-tile step for a 16-row q-subtile ---------------
__device__ __forceinline__ void attn_tile(
    const bf16 (*__restrict__ Ksh)[72], const bf16 (*__restrict__ Vsh)[72],
    bf16 (*__restrict__ Pw)[72], const bf16x8* qf, f32x4* o,
    float& m, float& l, int qi, int kk0, bool diag, int qrow, int grp) {
  f32x4 sc[4] = {};
  __builtin_amdgcn_s_setprio(1);
#pragma unroll
  for (int ch = 0; ch < 2; ++ch)
#pragma unroll
    for (int cb = 0; cb < 4; ++cb) {
      bf16x8 kf = *(const bf16x8*)&Ksh[cb * 16 + qrow][ch * 32 + grp * 8];
      sc[cb] = MFMA16(kf, qf[ch], sc[cb]);   // S^T[k][q]
    }
  __builtin_amdgcn_s_setprio(0);

  if (diag) {
#pragma unroll
    for (int cb = 0; cb < 4; ++cb)
#pragma unroll
      for (int r = 0; r < 4; ++r)
        if (kk0 + cb * 16 + grp * 4 + r > qi) sc[cb][r] = -1e30f;
  }

  float pm = sc[0][0];
#pragma unroll
  for (int cb = 0; cb < 4; ++cb)
#pragma unroll
    for (int r = 0; r < 4; ++r) pm = fmaxf(pm, sc[cb][r]);
  pm = fmaxf(pm, __shfl_xor(pm, 16));
  pm = fmaxf(pm, __shfl_xor(pm, 32));
  const float mn = fmaxf(m, pm);
  const float scl = exp2f(m - mn);
  m = mn;
  l *= scl;
#pragma unroll
  for (int cb = 0; cb < 4; ++cb) {
    bf16x4 pk;
#pragma unroll
    for (int r = 0; r < 4; ++r) {
      float p = exp2f(sc[cb][r] - mn);
      l += p;
      pk[r] = (bf16)p;
    }
    *(bf16x4*)&Pw[qrow][cb * 16 + grp * 4] = pk;
  }
#pragma unroll
  for (int hb = 0; hb < 4; ++hb)
#pragma unroll
    for (int r = 0; r < 4; ++r) o[hb][r] *= scl;

  __builtin_amdgcn_s_setprio(1);
#pragma unroll
  for (int ch = 0; ch < 2; ++ch) {
    bf16x8 pa = *(const bf16x8*)&Pw[qrow][ch * 32 + grp * 8];
#pragma unroll
    for (int hb = 0; hb < 4; ++hb) {
      bf16x8 vf = *(const bf16x8*)&Vsh[hb * 16 + qrow][ch * 32 + grp * 8];
      o[hb] = MFMA16(vf, pa, o[hb]);         // O^T[hd][q]
    }
  }
  __builtin_amdgcn_s_setprio(0);
}

// ---------------- flash attention, causal, 8 waves, k-parity split -------
// Block = 8 waves (512 thr) = 2 groups of 4. Group h handles k-tiles of
// parity h for BOTH tiles of the pair (tA=j, tB=31-j); each group stages its
// own K/V LDS tile (reg-staged, loads issued during compute of the prior
// round; barriers never drain vmcnt). Wave wl in each group owns q-rows
// [t*64+wl*16, +16). Worklists are 17/16 rounds for EVERY block -> uniform.
// End: 2-way flash merge (group1 -> LDS fp32 overlay, group0 combines).
// grid (32, 16): x = bh (fast -> XCD locality), y = j.
__global__ __launch_bounds__(512, 4)
void attn_k(const bf16* __restrict__ q, const bf16* __restrict__ k,
            const bf16* __restrict__ vt, bf16* __restrict__ out) {
  __shared__ __align__(16) char smem[55296];
  auto Ks = (bf16(*)[64][72])smem;                 // [2][64][72] bf16
  auto Vs = (bf16(*)[64][72])(smem + 18432);       // [2][64][72] bf16
  auto P  = (bf16(*)[16][72])(smem + 36864);       // [8][16][72] bf16
  auto MO = (float(*)[2][16][68])smem;             // overlay [4][2][16][68] f32
  auto ML = (float(*)[2][16][2])(smem + 36864);    // overlay [4][2][16][2] f32

  const int tid = threadIdx.x;
  const int w = tid >> 6, lane = tid & 63;
  const int h = w >> 2, wl = w & 3;                // group, pair-index
  const int qrow = lane & 15, grp = lane >> 4;
  const int bh = blockIdx.x, j = blockIdx.y;
  const int b = bh >> 4, hh = bh & (NH - 1);
  const int tA = j, tB = 31 - j;

  const bf16* qb = q + (size_t)bh * NS * NHD;
  const bf16* kb = k + (size_t)bh * NS * NHD;
  const bf16* vb = vt + (size_t)bh * NHD * NS;

  const int nA = (j >= h) ? (((j - h) >> 1) + 1) : 0;   // group's tile-A rounds
  const int nB = (((31 - j) - h) >> 1) + 1;             // group's tile-B rounds
  const int len = nA + nB;                              // 17 (h=0) or 16 (h=1)

  const int q0A = tA * 64 + wl * 16, q0B = tB * 64 + wl * 16;
  bf16x8 qfA[2], qfB[2];
#pragma unroll
  for (int ch = 0; ch < 2; ++ch) {
    qfA[ch] = *(const bf16x8*)&qb[(size_t)(q0A + qrow) * NHD + ch * 32 + grp * 8];
    qfB[ch] = *(const bf16x8*)&qb[(size_t)(q0B + qrow) * NHD + ch * 32 + grp * 8];
  }

  f32x4 oA[4] = {}, oB[4] = {};
  float mA = -1e30f, lA = 0.f, mB = -1e30f, lB = 0.f;

  // group-private staging slots: 256 threads cover 64x64 K + 64x64 V
  const int local = tid & 255;
  const int r0 = local >> 3, c0 = (local & 7) * 8;     // rows r0, r0+32

  bf16x8 ka0, ka1, va0, va1;
  auto load_round = [&](int r) {
    const bool isA = r < nA;
    const int kt = isA ? (h + 2 * r) : (h + 2 * (r - nA));
    const int kk0 = kt * 64;
    ka0 = *(const bf16x8*)&kb[(size_t)(kk0 + r0) * NHD + c0];
    ka1 = *(const bf16x8*)&kb[(size_t)(kk0 + r0 + 32) * NHD + c0];
    va0 = *(const bf16x8*)&vb[(size_t)r0 * NS + kk0 + c0];
    va1 = *(const bf16x8*)&vb[(size_t)(r0 + 32) * NS + kk0 + c0];
  };

  load_round(0);   // len >= 1 always (h=1: nB >= 8)
  for (int r = 0; r < 17; ++r) {
    const bool act = r < len;
    if (act) {
      *(bf16x8*)&Ks[h][r0][c0]      = ka0;
      *(bf16x8*)&Ks[h][r0 + 32][c0] = ka1;
      *(bf16x8*)&Vs[h][r0][c0]      = va0;
      *(bf16x8*)&Vs[h][r0 + 32][c0] = va1;
    }
    block_sync_lds();                 // publish LDS; global loads stay in flight
    const bool isA = r < nA;
    const int kt = isA ? (h + 2 * r) : (h + 2 * (r - nA));
    if (r + 1 < len) load_round(r + 1);   // issue next loads under compute
    if (act) {
      if (isA)
        attn_tile(Ks[h], Vs[h], P[w], qfA, oA, mA, lA,
                  q0A + qrow, kt * 64, kt == tA, qrow, grp);
      else
        attn_tile(Ks[h], Vs[h], P[w], qfB, oB, mB, lB,
                  q0B + qrow, kt * 64, kt == tB, qrow, grp);
    }
    block_sync_lds();                 // readers done before next round's writes
  }

  // reduce l across the 4 lane-groups sharing each q-row
  lA += __shfl_xor(lA, 16); lA += __shfl_xor(lA, 32);
  lB += __shfl_xor(lB, 16); lB += __shfl_xor(lB, 32);

  __syncthreads();   // all LDS traffic done before overlay reuse

  if (h == 1) {      // publish group-1 partials (fp32)
#pragma unroll
    for (int hb = 0; hb < 4; ++hb) {
      *(f32x4*)&MO[wl][0][qrow][hb * 16 + grp * 4] = oA[hb];
      *(f32x4*)&MO[wl][1][qrow][hb * 16 + grp * 4] = oB[hb];
    }
    if (grp == 0) {
      ML[wl][0][qrow][0] = mA; ML[wl][0][qrow][1] = lA;
      ML[wl][1][qrow][0] = mB; ML[wl][1][qrow][1] = lB;
    }
  }
  __syncthreads();

  if (h == 0) {      // merge + store
#pragma unroll
    for (int sub = 0; sub < 2; ++sub) {
      const float m0 = sub ? mB : mA, l0 = sub ? lB : lA;
      const f32x4* o0 = sub ? oB : oA;
      const float m1 = ML[wl][sub][qrow][0], l1 = ML[wl][sub][qrow][1];
      const float mm = fmaxf(m0, m1);
      const float s0 = exp2f(m0 - mm), s1 = exp2f(m1 - mm);
      const float inv = 1.f / (l0 * s0 + l1 * s1);
      const int s = (sub ? q0B : q0A) + qrow;
      bf16* op = out + (size_t)(b * NS + s) * ND + hh * NHD + grp * 4;
#pragma unroll
      for (int hb = 0; hb < 4; ++hb) {
        f32x4 o1 = *(const f32x4*)&MO[wl][sub][qrow][hb * 16 + grp * 4];
        bf16x4 ov = { (bf16)((o0[hb][0] * s0 + o1[0] * s1) * inv),
                      (bf16)((o0[hb][1] * s0 + o1[1] * s1) * inv),
                      (bf16)((o0[hb][2] * s0 + o1[2] * s1) * inv),
                      (bf16)((o0[hb][3] * s0 + o1[3] * s1) * inv) };
        *(bf16x4*)&op[hb * 16] = ov;
      }
    }
  }
}

// -------------------------------------------------------------------------
extern "C" void kernel_launch(void* const* d_in, const int* in_sizes, int n_in,
                              void* d_out, int out_size, void* d_ws, size_t ws_size,
                              hipStream_t stream) {
  const float* Q  = (const float*)d_in[0];
  const float* K  = (const float*)d_in[1];
  const float* V  = (const float*)d_in[2];
  // d_in[3] = mask (causal, known analytically -> unused)
  const float* fc = (const float*)d_in[4];
  const float* fs = (const float*)d_in[5];
  const float* wq = (const float*)d_in[6];
  const float* bq = (const float*)d_in[7];
  const float* wk = (const float*)d_in[8];
  const float* bk = (const float*)d_in[9];
  const float* wv = (const float*)d_in[10];
  const float* bv = (const float*)d_in[11];
  const float* wo = (const float*)d_in[12];
  const float* bo = (const float*)d_in[13];
  float* out = (float*)d_out;
  bf16* ws = (bf16*)d_ws;

  const size_t MB_ = 1024 * 1024;  // elements
  bf16* Qbf  = ws;                     // 3 x 4M elems (Q,K,V bf16)
  bf16* Wqkv = ws + 12 * MB_;          // 3 x 1M (wq, wk, wv)
  bf16* Wo   = ws + 15 * MB_;          // 1M
  bf16* qp   = ws + 16 * MB_;          // q' [BH,S,HD] 4M
  bf16* kp   = ws + 20 * MB_;          // k' 4M
  bf16* vp   = ws + 24 * MB_;          // v' 4M
  bf16* vtp  = ws + 28 * MB_;          // v transposed [BH,HD,S] 4M
  bf16* aout = ws + 32 * MB_;          // attention output [M, D] 4M

  cvt3<<<dim3(4096, 3), 256, 0, stream>>>(Q, K, V, Qbf, 1048576);
  cvt_w4<<<dim3(1024, 4), 256, 0, stream>>>(wq, wk, wv, wo, Wqkv, 262144);

  gemm_nt<0><<<dim3(8, 32, 3), 256, 0, stream>>>(Qbf, Wqkv, bq, bk, bv, fc, fs, qp, nullptr);

  transpose_v<<<dim3(32, 32), 256, 0, stream>>>(vp, vtp);

  attn_k<<<dim3(32, 16), 512, 0, stream>>>(qp, kp, vtp, aout);

  gemm_nt<1><<<dim3(8, 32, 1), 256, 0, stream>>>(aout, Wo, bo, bo, bo, fc, fs, nullptr, out);
}